// Round 1
// baseline (966.427 us; speedup 1.0000x reference)
//
#include <hip/hip_runtime.h>

#define NN 20000
#define EE 320000
#define DD 128
#define LL 5
#define EVV 5
#define BNEPS 1e-5f

// ---------------- CSR build ----------------

__global__ __launch_bounds__(256) void count_kernel(const int* __restrict__ dst,
                                                    int* __restrict__ deg) {
    int e = blockIdx.x * 256 + threadIdx.x;
    if (e < EE) atomicAdd(&deg[dst[e]], 1);
}

__global__ __launch_bounds__(1024) void scan_kernel(const int* __restrict__ deg,
                                                    int* __restrict__ offs,
                                                    int* __restrict__ pos) {
    __shared__ int lds[1024];
    int t = threadIdx.x;
    int base = t * 20;
    int s = 0;
    for (int i = 0; i < 20; i++) {
        int j = base + i;
        if (j < NN) s += deg[j];
    }
    lds[t] = s;
    __syncthreads();
    for (int off = 1; off < 1024; off <<= 1) {
        int v = (t >= off) ? lds[t - off] : 0;
        __syncthreads();
        lds[t] += v;
        __syncthreads();
    }
    int run = lds[t] - s;  // exclusive prefix
    for (int i = 0; i < 20; i++) {
        int j = base + i;
        if (j < NN) {
            offs[j] = run;
            pos[j] = run;
            run += deg[j];
        }
    }
}

__global__ __launch_bounds__(256) void scatter_kernel(const int* __restrict__ src,
                                                      const int* __restrict__ dst,
                                                      const int* __restrict__ eattr,
                                                      int* __restrict__ pos,
                                                      int* __restrict__ ssrc,
                                                      int* __restrict__ sattr) {
    int e = blockIdx.x * 256 + threadIdx.x;
    if (e < EE) {
        int d = dst[e];
        int p = atomicAdd(&pos[d], 1);
        ssrc[p] = src[e];
        sattr[p] = eattr[e];
    }
}

// ---------------- node embedding gather ----------------

__global__ __launch_bounds__(256) void embed_kernel(const int* __restrict__ x,
                                                    const float4* __restrict__ e1,
                                                    const float4* __restrict__ e2,
                                                    float4* __restrict__ h1,
                                                    float4* __restrict__ h2) {
    int idx = blockIdx.x * 256 + threadIdx.x;  // < NN*32 exactly
    int r = idx >> 5, c = idx & 31;
    int v = x[r];
    h1[idx] = e1[v * 32 + c];
    h2[idx] = e2[v * 32 + c];
}

// ---------------- aggregation (gather over CSR), both towers ----------------

__global__ __launch_bounds__(256) void aggregate_kernel(
    const float* __restrict__ h1, const float* __restrict__ h2,
    const float* __restrict__ etab, int layer,
    const int* __restrict__ offs, const int* __restrict__ deg,
    const int* __restrict__ ssrc, const int* __restrict__ sattr,
    float* __restrict__ agg1, float* __restrict__ agg2,
    float* __restrict__ stats) {
    int tid = threadIdx.x;
    if (blockIdx.x == 0) {  // zero the BN-stat accumulators for this layer
        stats[tid] = 0.f;
        stats[tid + 256] = 0.f;
    }
    int node = blockIdx.x * 4 + (tid >> 6);  // grid 5000*4 == NN exactly
    int lane = tid & 63;
    const float2* h1v = (const float2*)h1;
    const float2* h2v = (const float2*)h2;
    const float2* t1v = (const float2*)(etab + (size_t)(0 * LL + layer) * EVV * DD);
    const float2* t2v = (const float2*)(etab + (size_t)(1 * LL + layer) * EVV * DD);
    int off = offs[node];
    int dg = deg[node];
    float2 a1; a1.x = a1.y = 0.f;
    float2 a2; a2.x = a2.y = 0.f;
    for (int i = 0; i < dg; i++) {
        int e = off + i;
        int s = ssrc[e];
        int ea = sattr[e];
        float2 v1 = h1v[(size_t)s * 64 + lane];
        float2 e1 = t1v[ea * 64 + lane];
        float m;
        m = v1.x + e1.x; a1.x += (m > 0.f) ? m : 0.f;
        m = v1.y + e1.y; a1.y += (m > 0.f) ? m : 0.f;
        float2 v2 = h2v[(size_t)s * 64 + lane];
        float2 e2 = t2v[ea * 64 + lane];
        m = v2.x + e2.x; a2.x += (m > 0.f) ? m : 0.f;
        m = v2.y + e2.y; a2.y += (m > 0.f) ? m : 0.f;
    }
    ((float2*)agg1)[(size_t)node * 64 + lane] = a1;
    ((float2*)agg2)[(size_t)node * 64 + lane] = a2;
}

// ---------------- GEMM y = ((1+eps)h + agg) @ W^T + b, in-place over agg, + BN stats ----------------

__global__ __launch_bounds__(256) void gemm_stats_kernel(
    const float* __restrict__ h1g, const float* __restrict__ h2g,
    float* __restrict__ agg1, float* __restrict__ agg2,
    const float* __restrict__ Wall, const float* __restrict__ ball,
    const float* __restrict__ epsall, int layer,
    float* __restrict__ stats) {
    __shared__ float4 uS[64 * 32];
    __shared__ float4 redS[8 * 32];
    __shared__ float4 redQ[8 * 32];
    int tid = threadIdx.x;
    int tower = blockIdx.y;
    const float* h = tower ? h2g : h1g;
    float* agg = tower ? agg2 : agg1;
    const float4* W4 = (const float4*)(Wall + (size_t)(tower * LL + layer) * DD * DD);
    const float4* b4p = (const float4*)(ball + (size_t)(tower * LL + layer) * DD);
    float epv = 1.0f + epsall[tower * LL + layer];
    int row0 = blockIdx.x * 64;
    const float4* h4 = (const float4*)h;
    float4* agg4 = (float4*)agg;

#pragma unroll
    for (int i = 0; i < 8; i++) {
        int idx = i * 256 + tid;
        int r = idx >> 5, c4 = idx & 31;
        int row = row0 + r;
        float4 u;
        if (row < NN) {
            float4 hv = h4[(size_t)row * 32 + c4];
            float4 av = agg4[(size_t)row * 32 + c4];
            u.x = epv * hv.x + av.x;
            u.y = epv * hv.y + av.y;
            u.z = epv * hv.z + av.z;
            u.w = epv * hv.w + av.w;
        } else {
            u.x = u.y = u.z = u.w = 0.f;
        }
        uS[r * 32 + c4] = u;
    }
    __syncthreads();

    int col_t = tid & 31, row_t = tid >> 5;
    int c0 = col_t * 4;
    int rb = row_t * 8;
    float4 acc[8];
#pragma unroll
    for (int rr = 0; rr < 8; rr++) { acc[rr].x = acc[rr].y = acc[rr].z = acc[rr].w = 0.f; }

#pragma unroll 4
    for (int k = 0; k < 32; k++) {
        float4 w0 = W4[(c0 + 0) * 32 + k];
        float4 w1 = W4[(c0 + 1) * 32 + k];
        float4 w2 = W4[(c0 + 2) * 32 + k];
        float4 w3 = W4[(c0 + 3) * 32 + k];
#pragma unroll
        for (int rr = 0; rr < 8; rr++) {
            float4 u = uS[(rb + rr) * 32 + k];
            acc[rr].x += u.x * w0.x + u.y * w0.y + u.z * w0.z + u.w * w0.w;
            acc[rr].y += u.x * w1.x + u.y * w1.y + u.z * w1.z + u.w * w1.w;
            acc[rr].z += u.x * w2.x + u.y * w2.y + u.z * w2.z + u.w * w2.w;
            acc[rr].w += u.x * w3.x + u.y * w3.y + u.z * w3.z + u.w * w3.w;
        }
    }

    float4 bv = b4p[col_t];
    float4 s, q;
    s.x = s.y = s.z = s.w = 0.f;
    q.x = q.y = q.z = q.w = 0.f;
#pragma unroll
    for (int rr = 0; rr < 8; rr++) {
        int row = row0 + rb + rr;
        float4 y;
        y.x = acc[rr].x + bv.x;
        y.y = acc[rr].y + bv.y;
        y.z = acc[rr].z + bv.z;
        y.w = acc[rr].w + bv.w;
        if (row < NN) {
            agg4[(size_t)row * 32 + col_t] = y;
            s.x += y.x; s.y += y.y; s.z += y.z; s.w += y.w;
            q.x += y.x * y.x; q.y += y.y * y.y; q.z += y.z * y.z; q.w += y.w * y.w;
        }
    }
    redS[row_t * 32 + col_t] = s;
    redQ[row_t * 32 + col_t] = q;
    __syncthreads();
    if (row_t == 0) {
        float4 S = redS[col_t], Q = redQ[col_t];
#pragma unroll
        for (int j = 1; j < 8; j++) {
            float4 a = redS[j * 32 + col_t], b = redQ[j * 32 + col_t];
            S.x += a.x; S.y += a.y; S.z += a.z; S.w += a.w;
            Q.x += b.x; Q.y += b.y; Q.z += b.z; Q.w += b.w;
        }
        float* sb = stats + tower * 256;
        atomicAdd(&sb[c0 + 0], S.x);
        atomicAdd(&sb[c0 + 1], S.y);
        atomicAdd(&sb[c0 + 2], S.z);
        atomicAdd(&sb[c0 + 3], S.w);
        atomicAdd(&sb[128 + c0 + 0], Q.x);
        atomicAdd(&sb[128 + c0 + 1], Q.y);
        atomicAdd(&sb[128 + c0 + 2], Q.z);
        atomicAdd(&sb[128 + c0 + 3], Q.w);
    }
}

// ---------------- BN finalize: fold mean/var/gamma/beta into scale+shift ----------------

__global__ __launch_bounds__(256) void finalize_kernel(const float* __restrict__ stats,
                                                       const float* __restrict__ gall,
                                                       const float* __restrict__ btall,
                                                       int layer,
                                                       float* __restrict__ stt) {
    int t = threadIdx.x;  // 256 = 2 towers x 128 ch
    int tower = t >> 7, ch = t & 127;
    float sum = stats[tower * 256 + ch];
    float sq = stats[tower * 256 + 128 + ch];
    const float inv = 1.0f / (float)NN;
    float mu = sum * inv;
    float var = sq * inv - mu * mu;
    float rs = rsqrtf(var + BNEPS);
    float g = gall[(size_t)(tower * LL + layer) * DD + ch];
    float be = btall[(size_t)(tower * LL + layer) * DD + ch];
    float sc = rs * g;
    stt[tower * 256 + ch] = sc;
    stt[tower * 256 + 128 + ch] = be - mu * sc;
}

// ---------------- BN apply + ReLU + cross-stitch ----------------

__global__ __launch_bounds__(256) void bn_cross_kernel(
    const float4* __restrict__ a1, const float4* __restrict__ a2,
    float4* __restrict__ o1, float4* __restrict__ o2,
    const float* __restrict__ stt, const float* __restrict__ cross,
    int layer, int dorelu) {
    int idx = blockIdx.x * 256 + threadIdx.x;  // < NN*32 exactly
    int c4 = idx & 31;
    const float4* st4 = (const float4*)stt;
    float4 s1 = st4[c4], t1 = st4[32 + c4], s2 = st4[64 + c4], t2 = st4[96 + c4];
    float c00 = cross[layer * 4 + 0];
    float c01 = cross[layer * 4 + 1];
    float c10 = cross[layer * 4 + 2];
    float c11 = cross[layer * 4 + 3];
    float4 v1 = a1[idx], v2 = a2[idx];
    float4 r1, r2;
    float x1, x2, n1, n2;

    x1 = v1.x * s1.x + t1.x; x2 = v2.x * s2.x + t2.x;
    if (dorelu) { x1 = fmaxf(x1, 0.f); x2 = fmaxf(x2, 0.f); }
    n1 = c00 * x1 + c01 * x2; n2 = c10 * n1 + c11 * x2;
    r1.x = n1; r2.x = n2;

    x1 = v1.y * s1.y + t1.y; x2 = v2.y * s2.y + t2.y;
    if (dorelu) { x1 = fmaxf(x1, 0.f); x2 = fmaxf(x2, 0.f); }
    n1 = c00 * x1 + c01 * x2; n2 = c10 * n1 + c11 * x2;
    r1.y = n1; r2.y = n2;

    x1 = v1.z * s1.z + t1.z; x2 = v2.z * s2.z + t2.z;
    if (dorelu) { x1 = fmaxf(x1, 0.f); x2 = fmaxf(x2, 0.f); }
    n1 = c00 * x1 + c01 * x2; n2 = c10 * n1 + c11 * x2;
    r1.z = n1; r2.z = n2;

    x1 = v1.w * s1.w + t1.w; x2 = v2.w * s2.w + t2.w;
    if (dorelu) { x1 = fmaxf(x1, 0.f); x2 = fmaxf(x2, 0.f); }
    n1 = c00 * x1 + c01 * x2; n2 = c10 * n1 + c11 * x2;
    r1.w = n1; r2.w = n2;

    o1[idx] = r1;
    o2[idx] = r2;
}

// ---------------- launcher ----------------

extern "C" void kernel_launch(void* const* d_in, const int* in_sizes, int n_in,
                              void* d_out, int out_size, void* d_ws, size_t ws_size,
                              hipStream_t stream) {
    const int* x = (const int*)d_in[0];
    const int* eidx = (const int*)d_in[1];
    const int* eattr = (const int*)d_in[2];
    const float* emb1 = (const float*)d_in[3];
    const float* emb2 = (const float*)d_in[4];
    const float* etab = (const float*)d_in[5];
    const float* epsv = (const float*)d_in[6];
    const float* Wall = (const float*)d_in[7];
    const float* ball = (const float*)d_in[8];
    const float* gall = (const float*)d_in[9];
    const float* btall = (const float*)d_in[10];
    const float* cross = (const float*)d_in[11];
    float* out = (float*)d_out;

    const size_t ND = (size_t)NN * DD;  // 2,560,000
    char* p = (char*)d_ws;
    float* h1 = (float*)p;   p += ND * 4;
    float* h2 = (float*)p;   p += ND * 4;
    float* agg1 = (float*)p; p += ND * 4;
    float* agg2 = (float*)p; p += ND * 4;
    int* deg = (int*)p;      p += (size_t)NN * 4;
    int* offs = (int*)p;     p += (size_t)NN * 4;
    int* pos = (int*)p;      p += (size_t)NN * 4;
    int* ssrc = (int*)p;     p += (size_t)EE * 4;
    int* sattr = (int*)p;    p += (size_t)EE * 4;
    float* stats = (float*)p; p += 512 * 4;
    float* stt = (float*)p;   p += 512 * 4;

    const int* src = eidx;
    const int* dst = eidx + EE;

    hipMemsetAsync(deg, 0, (size_t)NN * 4, stream);
    count_kernel<<<EE / 256, 256, 0, stream>>>(dst, deg);
    scan_kernel<<<1, 1024, 0, stream>>>(deg, offs, pos);
    scatter_kernel<<<EE / 256, 256, 0, stream>>>(src, dst, eattr, pos, ssrc, sattr);
    embed_kernel<<<(NN * 32) / 256, 256, 0, stream>>>(
        x, (const float4*)emb1, (const float4*)emb2, (float4*)h1, (float4*)h2);

    for (int l = 0; l < LL; l++) {
        aggregate_kernel<<<NN / 4, 256, 0, stream>>>(h1, h2, etab, l, offs, deg,
                                                     ssrc, sattr, agg1, agg2, stats);
        dim3 g((NN + 63) / 64, 2);
        gemm_stats_kernel<<<g, 256, 0, stream>>>(h1, h2, agg1, agg2, Wall, ball,
                                                 epsv, l, stats);
        finalize_kernel<<<1, 256, 0, stream>>>(stats, gall, btall, l, stt);
        float* o1 = (l == LL - 1) ? out : h1;
        float* o2 = (l == LL - 1) ? out + ND : h2;
        bn_cross_kernel<<<(NN * 32) / 256, 256, 0, stream>>>(
            (const float4*)agg1, (const float4*)agg2, (float4*)o1, (float4*)o2,
            stt, cross, l, (l < LL - 1) ? 1 : 0);
    }
}

// Round 2
// 624.054 us; speedup vs baseline: 1.5486x; 1.5486x over previous
//
#include <hip/hip_runtime.h>

#define NN 20000
#define EE 320000
#define DD 128
#define LL 5
#define EVV 5
#define BNEPS 1e-5f

typedef __attribute__((ext_vector_type(8))) short bf8_t;   // 8 bf16 (4 VGPRs)
typedef __attribute__((ext_vector_type(4))) float f4_t;    // 4 fp32

__device__ inline unsigned short f2bf(float f) {
    union { float f; unsigned u; } v;
    v.f = f;
    unsigned r = v.u + 0x7fffu + ((v.u >> 16) & 1u);  // RTN-even
    return (unsigned short)(r >> 16);
}

// ---------------- CSR build ----------------

__global__ __launch_bounds__(256) void count_kernel(const int* __restrict__ dst,
                                                    int* __restrict__ deg) {
    int e = blockIdx.x * 256 + threadIdx.x;
    if (e < EE) atomicAdd(&deg[dst[e]], 1);
}

__global__ __launch_bounds__(1024) void scan_kernel(const int* __restrict__ deg,
                                                    int* __restrict__ offs,
                                                    int* __restrict__ pos) {
    __shared__ int lds[1024];
    int t = threadIdx.x;
    int base = t * 20;
    int s = 0;
    for (int i = 0; i < 20; i++) {
        int j = base + i;
        if (j < NN) s += deg[j];
    }
    lds[t] = s;
    __syncthreads();
    for (int off = 1; off < 1024; off <<= 1) {
        int v = (t >= off) ? lds[t - off] : 0;
        __syncthreads();
        lds[t] += v;
        __syncthreads();
    }
    int run = lds[t] - s;  // exclusive prefix
    for (int i = 0; i < 20; i++) {
        int j = base + i;
        if (j < NN) {
            offs[j] = run;
            pos[j] = run;
            run += deg[j];
        }
    }
}

__global__ __launch_bounds__(256) void scatter_kernel(const int* __restrict__ src,
                                                      const int* __restrict__ dst,
                                                      const int* __restrict__ eattr,
                                                      int* __restrict__ pos,
                                                      int* __restrict__ ssrc,
                                                      int* __restrict__ sattr) {
    int e = blockIdx.x * 256 + threadIdx.x;
    if (e < EE) {
        int d = dst[e];
        int p = atomicAdd(&pos[d], 1);
        ssrc[p] = src[e];
        sattr[p] = eattr[e];
    }
}

// ---------------- node embedding gather ----------------

__global__ __launch_bounds__(256) void embed_kernel(const int* __restrict__ x,
                                                    const float4* __restrict__ e1,
                                                    const float4* __restrict__ e2,
                                                    float4* __restrict__ h1,
                                                    float4* __restrict__ h2) {
    int idx = blockIdx.x * 256 + threadIdx.x;  // < NN*32 exactly
    int r = idx >> 5, c = idx & 31;
    int v = x[r];
    h1[idx] = e1[v * 32 + c];
    h2[idx] = e2[v * 32 + c];
}

// ---------------- W fp32 -> bf16 convert (once per call) ----------------

__global__ __launch_bounds__(256) void convert_w_kernel(const float4* __restrict__ Wall,
                                                        ushort4* __restrict__ Wb) {
    int i = blockIdx.x * 256 + threadIdx.x;  // 2*5*128*128/4 = 40960 exactly (160 blocks)
    float4 w = Wall[i];
    ushort4 o;
    o.x = f2bf(w.x); o.y = f2bf(w.y); o.z = f2bf(w.z); o.w = f2bf(w.w);
    Wb[i] = o;
}

// ---------------- aggregation (gather over CSR), both towers, emits u in bf16 ----------------

__global__ __launch_bounds__(256) void aggregate_kernel(
    const float* __restrict__ h1, const float* __restrict__ h2,
    const float* __restrict__ etab, int layer,
    const int* __restrict__ offs, const int* __restrict__ deg,
    const int* __restrict__ ssrc, const int* __restrict__ sattr,
    const float* __restrict__ epsall,
    unsigned short* __restrict__ u1b, unsigned short* __restrict__ u2b,
    float* __restrict__ stats) {
    int tid = threadIdx.x;
    if (blockIdx.x == 0) {  // zero BN-stat accumulators for this layer
        stats[tid] = 0.f;
        stats[tid + 256] = 0.f;
    }
    int node = blockIdx.x * 4 + (tid >> 6);  // grid 5000*4 == NN exactly
    int lane = tid & 63;
    int half = lane >> 5;       // which edge of the pair
    int c = lane & 31;          // float4 column
    const float4* h1v = (const float4*)h1;
    const float4* h2v = (const float4*)h2;
    const float4* t1v = (const float4*)(etab + (size_t)(0 * LL + layer) * EVV * DD);
    const float4* t2v = (const float4*)(etab + (size_t)(1 * LL + layer) * EVV * DD);
    int off = offs[node];
    int dg = deg[node];
    float4 a1; a1.x = a1.y = a1.z = a1.w = 0.f;
    float4 a2; a2.x = a2.y = a2.z = a2.w = 0.f;
#pragma unroll 2
    for (int i = 0; i < dg; i += 2) {
        int j = i + half;
        bool valid = (j < dg);
        int e = off + (valid ? j : 0);
        int s = ssrc[e];
        int ea = sattr[e];
        float4 v1 = h1v[(size_t)s * 32 + c];
        float4 e1 = t1v[ea * 32 + c];
        float4 v2 = h2v[(size_t)s * 32 + c];
        float4 e2 = t2v[ea * 32 + c];
        if (valid) {
            a1.x += fmaxf(v1.x + e1.x, 0.f);
            a1.y += fmaxf(v1.y + e1.y, 0.f);
            a1.z += fmaxf(v1.z + e1.z, 0.f);
            a1.w += fmaxf(v1.w + e1.w, 0.f);
            a2.x += fmaxf(v2.x + e2.x, 0.f);
            a2.y += fmaxf(v2.y + e2.y, 0.f);
            a2.z += fmaxf(v2.z + e2.z, 0.f);
            a2.w += fmaxf(v2.w + e2.w, 0.f);
        }
    }
    // combine the two half-wave partials (same column, different edges)
    a1.x += __shfl_xor(a1.x, 32, 64);
    a1.y += __shfl_xor(a1.y, 32, 64);
    a1.z += __shfl_xor(a1.z, 32, 64);
    a1.w += __shfl_xor(a1.w, 32, 64);
    a2.x += __shfl_xor(a2.x, 32, 64);
    a2.y += __shfl_xor(a2.y, 32, 64);
    a2.z += __shfl_xor(a2.z, 32, 64);
    a2.w += __shfl_xor(a2.w, 32, 64);

    // u = (1+eps)*h_self + agg, bf16 RTN. half 0 writes tower1, half 1 writes tower2.
    float ep = 1.0f + epsall[half * LL + layer];
    float4 hs = half ? h2v[(size_t)node * 32 + c] : h1v[(size_t)node * 32 + c];
    float4 aa = half ? a2 : a1;
    float4 u;
    u.x = ep * hs.x + aa.x;
    u.y = ep * hs.y + aa.y;
    u.z = ep * hs.z + aa.z;
    u.w = ep * hs.w + aa.w;
    ushort4 ub;
    ub.x = f2bf(u.x); ub.y = f2bf(u.y); ub.z = f2bf(u.z); ub.w = f2bf(u.w);
    ushort4* uo = (ushort4*)(half ? u2b : u1b);
    uo[(size_t)node * 32 + c] = ub;
}

// ---------------- MFMA GEMM: y = u_bf16 @ W^T + b (fp32 out, into h buffers) + BN stats ----------------

__global__ __launch_bounds__(256) void gemm_mfma_kernel(
    const unsigned short* __restrict__ u1b, const unsigned short* __restrict__ u2b,
    const unsigned short* __restrict__ Wb, const float* __restrict__ ball, int layer,
    float* __restrict__ y1, float* __restrict__ y2,
    float* __restrict__ stats) {
    __shared__ float sS[DD];
    __shared__ float sQ[DD];
    int tid = threadIdx.x;
    int tower = blockIdx.y;
    const unsigned short* ub = tower ? u2b : u1b;
    float* y = tower ? y2 : y1;
    const bf8_t* W8 = (const bf8_t*)(Wb + (size_t)(tower * LL + layer) * DD * DD);
    const float* bias = ball + (size_t)(tower * LL + layer) * DD;
    const bf8_t* u8 = (const bf8_t*)ub;

    if (tid < DD) { sS[tid] = 0.f; sQ[tid] = 0.f; }
    __syncthreads();

    int wave = tid >> 6, lane = tid & 63;
    int quad = lane >> 4, m = lane & 15;
    int row_base = blockIdx.x * 64 + wave * 16;

    f4_t acc[8];
#pragma unroll
    for (int nt = 0; nt < 8; nt++) {
        acc[nt][0] = 0.f; acc[nt][1] = 0.f; acc[nt][2] = 0.f; acc[nt][3] = 0.f;
    }

    // A rows past NN read garbage (within ws) but only contaminate unstored D rows.
    int aidx = (row_base + m) * 16;  // row stride = 128 bf16 = 16 bf8 units
#pragma unroll
    for (int kt = 0; kt < 4; kt++) {
        bf8_t a = u8[aidx + kt * 4 + quad];
#pragma unroll
        for (int nt = 0; nt < 8; nt++) {
            bf8_t b = W8[(nt * 16 + m) * 16 + kt * 4 + quad];
            acc[nt] = __builtin_amdgcn_mfma_f32_16x16x32_bf16(a, b, acc[nt], 0, 0, 0);
        }
    }

    // Epilogue: D layout col = lane&15, row = quad*4 + reg
#pragma unroll
    for (int nt = 0; nt < 8; nt++) {
        int col = nt * 16 + m;
        float bv = bias[col];
        float s = 0.f, q = 0.f;
#pragma unroll
        for (int r = 0; r < 4; r++) {
            int row = row_base + quad * 4 + r;
            if (row < NN) {
                float v = acc[nt][r] + bv;
                y[(size_t)row * DD + col] = v;
                s += v;
                q += v * v;
            }
        }
        atomicAdd(&sS[col], s);
        atomicAdd(&sQ[col], q);
    }
    __syncthreads();
    if (tid < DD) {
        atomicAdd(&stats[tower * 256 + tid], sS[tid]);
        atomicAdd(&stats[tower * 256 + 128 + tid], sQ[tid]);
    }
}

// ---------------- BN finalize: fold mean/var/gamma/beta into scale+shift ----------------

__global__ __launch_bounds__(256) void finalize_kernel(const float* __restrict__ stats,
                                                       const float* __restrict__ gall,
                                                       const float* __restrict__ btall,
                                                       int layer,
                                                       float* __restrict__ stt) {
    int t = threadIdx.x;  // 256 = 2 towers x 128 ch
    int tower = t >> 7, ch = t & 127;
    float sum = stats[tower * 256 + ch];
    float sq = stats[tower * 256 + 128 + ch];
    const float inv = 1.0f / (float)NN;
    float mu = sum * inv;
    float var = sq * inv - mu * mu;
    float rs = rsqrtf(var + BNEPS);
    float g = gall[(size_t)(tower * LL + layer) * DD + ch];
    float be = btall[(size_t)(tower * LL + layer) * DD + ch];
    float sc = rs * g;
    stt[tower * 256 + ch] = sc;
    stt[tower * 256 + 128 + ch] = be - mu * sc;
}

// ---------------- BN apply + ReLU + cross-stitch (in-place capable: no restrict) ----------------

__global__ __launch_bounds__(256) void bn_cross_kernel(
    const float4* a1, const float4* a2,
    float4* o1, float4* o2,
    const float* __restrict__ stt, const float* __restrict__ cross,
    int layer, int dorelu) {
    int idx = blockIdx.x * 256 + threadIdx.x;  // < NN*32 exactly
    int c4 = idx & 31;
    const float4* st4 = (const float4*)stt;
    float4 s1 = st4[c4], t1 = st4[32 + c4], s2 = st4[64 + c4], t2 = st4[96 + c4];
    float c00 = cross[layer * 4 + 0];
    float c01 = cross[layer * 4 + 1];
    float c10 = cross[layer * 4 + 2];
    float c11 = cross[layer * 4 + 3];
    float4 v1 = a1[idx], v2 = a2[idx];
    float4 r1, r2;
    float x1, x2, n1, n2;

    x1 = v1.x * s1.x + t1.x; x2 = v2.x * s2.x + t2.x;
    if (dorelu) { x1 = fmaxf(x1, 0.f); x2 = fmaxf(x2, 0.f); }
    n1 = c00 * x1 + c01 * x2; n2 = c10 * n1 + c11 * x2;
    r1.x = n1; r2.x = n2;

    x1 = v1.y * s1.y + t1.y; x2 = v2.y * s2.y + t2.y;
    if (dorelu) { x1 = fmaxf(x1, 0.f); x2 = fmaxf(x2, 0.f); }
    n1 = c00 * x1 + c01 * x2; n2 = c10 * n1 + c11 * x2;
    r1.y = n1; r2.y = n2;

    x1 = v1.z * s1.z + t1.z; x2 = v2.z * s2.z + t2.z;
    if (dorelu) { x1 = fmaxf(x1, 0.f); x2 = fmaxf(x2, 0.f); }
    n1 = c00 * x1 + c01 * x2; n2 = c10 * n1 + c11 * x2;
    r1.z = n1; r2.z = n2;

    x1 = v1.w * s1.w + t1.w; x2 = v2.w * s2.w + t2.w;
    if (dorelu) { x1 = fmaxf(x1, 0.f); x2 = fmaxf(x2, 0.f); }
    n1 = c00 * x1 + c01 * x2; n2 = c10 * n1 + c11 * x2;
    r1.w = n1; r2.w = n2;

    o1[idx] = r1;
    o2[idx] = r2;
}

// ---------------- launcher ----------------

extern "C" void kernel_launch(void* const* d_in, const int* in_sizes, int n_in,
                              void* d_out, int out_size, void* d_ws, size_t ws_size,
                              hipStream_t stream) {
    const int* x = (const int*)d_in[0];
    const int* eidx = (const int*)d_in[1];
    const int* eattr = (const int*)d_in[2];
    const float* emb1 = (const float*)d_in[3];
    const float* emb2 = (const float*)d_in[4];
    const float* etab = (const float*)d_in[5];
    const float* epsv = (const float*)d_in[6];
    const float* Wall = (const float*)d_in[7];
    const float* ball = (const float*)d_in[8];
    const float* gall = (const float*)d_in[9];
    const float* btall = (const float*)d_in[10];
    const float* cross = (const float*)d_in[11];
    float* out = (float*)d_out;

    const size_t ND = (size_t)NN * DD;  // 2,560,000
    char* p = (char*)d_ws;
    float* h1 = (float*)p;            p += ND * 4;
    float* h2 = (float*)p;            p += ND * 4;
    unsigned short* u1b = (unsigned short*)p; p += ND * 2;
    unsigned short* u2b = (unsigned short*)p; p += ND * 2;
    unsigned short* Wb = (unsigned short*)p;  p += (size_t)2 * LL * DD * DD * 2;
    int* deg = (int*)p;               p += (size_t)NN * 4;
    int* offs = (int*)p;              p += (size_t)NN * 4;
    int* pos = (int*)p;               p += (size_t)NN * 4;
    int* ssrc = (int*)p;              p += (size_t)EE * 4;
    int* sattr = (int*)p;             p += (size_t)EE * 4;
    float* stats = (float*)p;         p += 512 * 4;
    float* stt = (float*)p;           p += 512 * 4;

    const int* src = eidx;
    const int* dst = eidx + EE;

    hipMemsetAsync(deg, 0, (size_t)NN * 4, stream);
    count_kernel<<<EE / 256, 256, 0, stream>>>(dst, deg);
    scan_kernel<<<1, 1024, 0, stream>>>(deg, offs, pos);
    scatter_kernel<<<EE / 256, 256, 0, stream>>>(src, dst, eattr, pos, ssrc, sattr);
    embed_kernel<<<(NN * 32) / 256, 256, 0, stream>>>(
        x, (const float4*)emb1, (const float4*)emb2, (float4*)h1, (float4*)h2);
    convert_w_kernel<<<(2 * LL * DD * DD / 4) / 256, 256, 0, stream>>>(
        (const float4*)Wall, (ushort4*)Wb);

    for (int l = 0; l < LL; l++) {
        aggregate_kernel<<<NN / 4, 256, 0, stream>>>(h1, h2, etab, l, offs, deg,
                                                     ssrc, sattr, epsv, u1b, u2b, stats);
        dim3 g((NN + 63) / 64, 2);
        // y written over h buffers (h is dead after aggregate)
        gemm_mfma_kernel<<<g, 256, 0, stream>>>(u1b, u2b, Wb, ball, l, h1, h2, stats);
        finalize_kernel<<<1, 256, 0, stream>>>(stats, gall, btall, l, stt);
        float* o1 = (l == LL - 1) ? out : h1;
        float* o2 = (l == LL - 1) ? out + ND : h2;
        bn_cross_kernel<<<(NN * 32) / 256, 256, 0, stream>>>(
            (const float4*)h1, (const float4*)h2, (float4*)o1, (float4*)o2,
            stt, cross, l, (l < LL - 1) ? 1 : 0);
    }
}